// Round 1
// baseline (635.653 us; speedup 1.0000x reference)
//
#include <hip/hip_runtime.h>
#include <hip/hip_bf16.h>

// Problem dims (fixed by the reference)
#define Td 4096   // tokens
#define Hd 1024   // hidden
#define Fd 4096   // ffn
#define Ed 8      // experts
#define Rcap 8704 // 136*64 compacted-row capacity (>= 8192 + 8*63, padded to 64)

typedef __attribute__((ext_vector_type(8))) short bf16x8;   // MFMA A/B frag (4 VGPRs)
typedef __attribute__((ext_vector_type(4))) float f32x4;    // MFMA C/D frag
typedef __attribute__((ext_vector_type(8))) unsigned short u16x8;

__device__ __forceinline__ unsigned short f32_to_bf16(float x) {
  unsigned int u = __float_as_uint(x);
  unsigned int r = (u + 0x7FFFu + ((u >> 16) & 1u)) >> 16;
  return (unsigned short)r;
}

// ---------------- hidden f32 -> bf16 ----------------
__global__ __launch_bounds__(256) void cvt_bf16_kernel(const float* __restrict__ in,
                                                       unsigned short* __restrict__ outp, int n8) {
  int i = blockIdx.x * 256 + threadIdx.x;
  if (i >= n8) return;
  const float4* p = (const float4*)(in + (size_t)i * 8);
  float4 a = p[0], b = p[1];
  u16x8 o;
  o[0] = f32_to_bf16(a.x); o[1] = f32_to_bf16(a.y); o[2] = f32_to_bf16(a.z); o[3] = f32_to_bf16(a.w);
  o[4] = f32_to_bf16(b.x); o[5] = f32_to_bf16(b.y); o[6] = f32_to_bf16(b.z); o[7] = f32_to_bf16(b.w);
  *(u16x8*)(outp + (size_t)i * 8) = o;
}

// ---------------- weight transpose+convert: in [E][Rd][Cd] f32 -> out [E][Cd][Rd] bf16 ----------------
__global__ __launch_bounds__(256) void transpose_cvt_kernel(const float* __restrict__ in,
                                                            unsigned short* __restrict__ outp,
                                                            int Rdm, int Cdm) {
  __shared__ float tile[64][68];  // 68 stride: keeps float4 LDS stores 16B-aligned
  int tilesR = Rdm >> 6, tilesC = Cdm >> 6;
  int per = tilesR * tilesC;
  int bid = blockIdx.x;
  int e = bid / per; int rem = bid - e * per;
  int tr = rem / tilesC; int tc = rem - tr * tilesC;
  int r0 = tr << 6, c0 = tc << 6;
  int tid = threadIdx.x;
  int rr = tid >> 2, cq = (tid & 3) << 4;
  const float* src = in + ((size_t)e * Rdm + r0 + rr) * Cdm + c0 + cq;
  float4 v0 = ((const float4*)src)[0];
  float4 v1 = ((const float4*)src)[1];
  float4 v2 = ((const float4*)src)[2];
  float4 v3 = ((const float4*)src)[3];
  *(float4*)&tile[rr][cq + 0]  = v0;
  *(float4*)&tile[rr][cq + 4]  = v1;
  *(float4*)&tile[rr][cq + 8]  = v2;
  *(float4*)&tile[rr][cq + 12] = v3;
  __syncthreads();
  // out row (c0+rr), k-range [r0+cq, +16): coalesced 16B x2 stores
  u16x8 o0, o1;
#pragma unroll
  for (int j = 0; j < 8; j++) o0[j] = f32_to_bf16(tile[cq + j][rr]);
#pragma unroll
  for (int j = 0; j < 8; j++) o1[j] = f32_to_bf16(tile[cq + 8 + j][rr]);
  unsigned short* dst = outp + ((size_t)e * Cdm + c0 + rr) * Rdm + r0 + cq;
  *(u16x8*)dst = o0;
  *(u16x8*)(dst + 8) = o1;
}

// ---------------- routing ----------------
__global__ void init_meta_kernel(int* cnt) {
  if (threadIdx.x < Ed) cnt[threadIdx.x] = 0;
}

__global__ __launch_bounds__(256) void route_kernel(const int* __restrict__ sel,
                                                    const float* __restrict__ ew,
                                                    int* cnt, int* idxT, float* wgtT) {
  int t = blockIdx.x * 256 + threadIdx.x;
  if (t >= Td) return;
  int e0 = sel[t * 2], e1 = sel[t * 2 + 1];
  float w0 = ew[t * 2], w1 = ew[t * 2 + 1];
  if (e0 == e1) { w0 += w1; e1 = -1; }   // merge duplicate expert: one entry, summed weight
  if (e0 >= 0 && e0 < Ed) { int p = atomicAdd(&cnt[e0], 1); idxT[e0 * Td + p] = t; wgtT[e0 * Td + p] = w0; }
  if (e1 >= 0 && e1 < Ed) { int p = atomicAdd(&cnt[e1], 1); idxT[e1 * Td + p] = t; wgtT[e1 * Td + p] = w1; }
}

__global__ void scan_kernel(const int* cnt, int* off) {
  if (threadIdx.x == 0) {
    int acc = 0; off[0] = 0;
#pragma unroll
    for (int e = 0; e < Ed; e++) { acc += (cnt[e] + 63) & ~63; off[e + 1] = acc; }
  }
}

__global__ __launch_bounds__(256) void compact_kernel(const int* __restrict__ cnt,
                                                      const int* __restrict__ off,
                                                      const int* __restrict__ idxT,
                                                      const float* __restrict__ wgtT,
                                                      int* __restrict__ cidx,
                                                      float* __restrict__ cwgt) {
  int j = blockIdx.x * 256 + threadIdx.x;  // j in [0, Ed*Td)
  int e = j >> 12; int i = j & (Td - 1);
  int base = off[e], end = off[e + 1];
  int row = base + i;
  if (row < end) {
    if (i < cnt[e]) { cidx[row] = idxT[e * Td + i]; cwgt[row] = wgtT[e * Td + i]; }
    else            { cidx[row] = -1;               cwgt[row] = 0.f; }
  }
}

// ---------------- tiled MFMA GEMM (64x64 tile, BK=64, 4 waves) ----------------
// FIRST:  A = hbf[T][Hd] gathered by cidx, B = W1T[e][Fd][Hd], out = gelu(A*B + b1) -> hbuf (bf16)
// !FIRST: A = hbuf rows,                  B = W2T[e][Hd][Fd], out[t] += cw * (A*B + b2) (atomic f32)
template <bool FIRST, int KD, int NC>
__global__ __launch_bounds__(256) void gemm_kernel(const unsigned short* __restrict__ Abase,
                                                   const unsigned short* __restrict__ Bt,
                                                   const float* __restrict__ bias,
                                                   const int* __restrict__ cidx,
                                                   const float* __restrict__ cwgt,
                                                   const int* __restrict__ off,
                                                   unsigned short* __restrict__ hbuf,
                                                   float* __restrict__ outp) {
  int row0 = blockIdx.y << 6;
  int tot = off[Ed];
  if (row0 >= tot) return;              // tile entirely beyond active rows
  int e = 0;
  while (off[e + 1] <= row0) ++e;       // padded offsets are multiples of 64: tile never spans experts
  int n0 = blockIdx.x << 6;

  __shared__ unsigned short As[64][72]; // stride 72 bf16 = 144 B (16B-aligned, conflict-friendly)
  __shared__ unsigned short Bs[64][72];

  const int tid = threadIdx.x;
  const int sr = tid >> 2, sk = (tid & 3) << 4;  // staging: row, k-quad (16 bf16 per thread)

  bool avalid = true;
  const unsigned short* aptr;
  if (FIRST) {
    int t = cidx[row0 + sr];
    avalid = (t >= 0);
    aptr = Abase + (size_t)(avalid ? t : 0) * KD + sk;
  } else {
    aptr = Abase + (size_t)(row0 + sr) * KD + sk;
  }
  const unsigned short* bptr = Bt + ((size_t)e * NC + n0 + sr) * KD + sk;

  const int lane = tid & 63, wid = tid >> 6;
  const int wr = wid >> 1, wc = wid & 1;          // 2x2 wave grid, each wave owns 32x32
  const int fr = lane & 15, fk = (lane >> 4) << 3;

  f32x4 acc[2][2] = {};

  for (int k0 = 0; k0 < KD; k0 += 64) {
    uint4 a0v = make_uint4(0, 0, 0, 0), a1v = a0v;
    if (avalid) {
      a0v = ((const uint4*)(aptr + k0))[0];
      a1v = ((const uint4*)(aptr + k0))[1];
    }
    uint4 b0v = ((const uint4*)(bptr + k0))[0];
    uint4 b1v = ((const uint4*)(bptr + k0))[1];
    __syncthreads();
    *(uint4*)(&As[sr][sk])     = a0v;
    *(uint4*)(&As[sr][sk + 8]) = a1v;
    *(uint4*)(&Bs[sr][sk])     = b0v;
    *(uint4*)(&Bs[sr][sk + 8]) = b1v;
    __syncthreads();
#pragma unroll
    for (int ks = 0; ks < 64; ks += 32) {
      bf16x8 af0 = *(const bf16x8*)(&As[(wr << 5) + fr][ks + fk]);
      bf16x8 af1 = *(const bf16x8*)(&As[(wr << 5) + 16 + fr][ks + fk]);
      bf16x8 bg0 = *(const bf16x8*)(&Bs[(wc << 5) + fr][ks + fk]);
      bf16x8 bg1 = *(const bf16x8*)(&Bs[(wc << 5) + 16 + fr][ks + fk]);
      acc[0][0] = __builtin_amdgcn_mfma_f32_16x16x32_bf16(af0, bg0, acc[0][0], 0, 0, 0);
      acc[0][1] = __builtin_amdgcn_mfma_f32_16x16x32_bf16(af0, bg1, acc[0][1], 0, 0, 0);
      acc[1][0] = __builtin_amdgcn_mfma_f32_16x16x32_bf16(af1, bg0, acc[1][0], 0, 0, 0);
      acc[1][1] = __builtin_amdgcn_mfma_f32_16x16x32_bf16(af1, bg1, acc[1][1], 0, 0, 0);
    }
  }

  // epilogue — C/D layout (m89-verified): col = lane&15, row = (lane>>4)*4 + reg
#pragma unroll
  for (int mi = 0; mi < 2; mi++) {
#pragma unroll
    for (int ni = 0; ni < 2; ni++) {
      int col = n0 + (wc << 5) + (ni << 4) + fr;
      float bval = bias[e * NC + col];
      f32x4 v = acc[mi][ni];
#pragma unroll
      for (int r2 = 0; r2 < 4; r2++) {
        int row = row0 + (wr << 5) + (mi << 4) + ((lane >> 4) << 2) + r2;
        float x = v[r2] + bval;
        if (FIRST) {
          float g = 0.5f * x * (1.0f + erff(x * 0.70710678118654752f));  // exact GELU
          hbuf[(size_t)row * NC + col] = f32_to_bf16(g);
        } else {
          int tdst = cidx[row];
          if (tdst >= 0) {
            atomicAdd(outp + (size_t)tdst * NC + col, cwgt[row] * x);
          }
        }
      }
    }
  }
}

extern "C" void kernel_launch(void* const* d_in, const int* in_sizes, int n_in,
                              void* d_out, int out_size, void* d_ws, size_t ws_size,
                              hipStream_t stream) {
  const float* hidden = (const float*)d_in[0];
  const float* ew     = (const float*)d_in[1];
  const float* W1     = (const float*)d_in[2];
  const float* b1     = (const float*)d_in[3];
  const float* W2     = (const float*)d_in[4];
  const float* b2     = (const float*)d_in[5];
  const int*   sel    = (const int*)d_in[6];
  float* outp = (float*)d_out;

  // workspace layout (~204 MB)
  unsigned short* hbf  = (unsigned short*)d_ws;                  // [T][H] bf16        8 MB
  unsigned short* W1T  = hbf + (size_t)Td * Hd;                  // [E][F][H] bf16    64 MB
  unsigned short* W2T  = W1T + (size_t)Ed * Fd * Hd;             // [E][H][F] bf16    64 MB
  unsigned short* hbuf = W2T + (size_t)Ed * Hd * Fd;             // [Rcap][F] bf16    68 MB
  int*   cnt  = (int*)(hbuf + (size_t)Rcap * Fd);
  int*   off  = cnt + 16;
  int*   idxT = off + 16;
  float* wgtT = (float*)(idxT + Ed * Td);
  int*   cidx = (int*)(wgtT + Ed * Td);
  float* cwgt = (float*)(cidx + Rcap);

  (void)hipMemsetAsync(d_out, 0, (size_t)Td * Hd * sizeof(float), stream);

  cvt_bf16_kernel<<<(Td * Hd / 8 + 255) / 256, 256, 0, stream>>>(hidden, hbf, Td * Hd / 8);
  transpose_cvt_kernel<<<Ed * (Hd / 64) * (Fd / 64), 256, 0, stream>>>(W1, W1T, Hd, Fd);
  transpose_cvt_kernel<<<Ed * (Fd / 64) * (Hd / 64), 256, 0, stream>>>(W2, W2T, Fd, Hd);

  init_meta_kernel<<<1, 64, 0, stream>>>(cnt);
  route_kernel<<<Td / 256, 256, 0, stream>>>(sel, ew, cnt, idxT, wgtT);
  scan_kernel<<<1, 64, 0, stream>>>(cnt, off);
  compact_kernel<<<Ed * Td / 256, 256, 0, stream>>>(cnt, off, idxT, wgtT, cidx, cwgt);

  gemm_kernel<true, Hd, Fd><<<dim3(Fd / 64, Rcap / 64), 256, 0, stream>>>(
      hbf, W1T, b1, cidx, cwgt, off, hbuf, nullptr);
  gemm_kernel<false, Fd, Hd><<<dim3(Hd / 64, Rcap / 64), 256, 0, stream>>>(
      hbuf, W2T, b2, cidx, cwgt, off, nullptr, outp);
}